// Round 2
// 2995.472 us; speedup vs baseline: 1.4947x; 1.4947x over previous
//
#include <hip/hip_runtime.h>

// Causal self-attention fwd, B=2, H=16, S=2048, D=64.
// Inputs fp32 (dtype sniff kept as insurance from prior session).
// d_out = [out (B*H*S*D)] ++ [attention (B*H*S*S)], both fp32.
//
// Structure: one block (256 thr) per output row. This round: stall removal.
//  - PV: float4 V loads, 16 j-groups x 16 d-quads, 4-way unroll (16 loads in
//    flight/thread), accumulate unnormalized e, scale by inv at the end.
//  - Scores: Q row in 16 float4 regs (L1 broadcast), dual-j dot (32 loads in
//    flight), fused per-thread running max.
//  - Reductions: wave shfl_xor + 4-slot LDS; barriers 20 -> 3.
//  - Non-temporal attention stores (512 MiB stream; don't evict K/V from L2).

#define B_ 2
#define H_ 16
#define S_ 2048
#define D_ 64

typedef unsigned short u16;
typedef unsigned int   u32;
typedef float f32x4 __attribute__((ext_vector_type(4)));   // native vec for nt-store

__device__ __forceinline__ float bf2f(u16 h) {
    union { u32 u; float f; } x; x.u = ((u32)h) << 16; return x.f;
}

__device__ __forceinline__ float wred_max(float v) {
    #pragma unroll
    for (int off = 32; off > 0; off >>= 1) v = fmaxf(v, __shfl_xor(v, off, 64));
    return v;
}

__device__ __forceinline__ float wred_sum(float v) {
    #pragma unroll
    for (int off = 32; off > 0; off >>= 1) v += __shfl_xor(v, off, 64);
    return v;
}

__global__ __launch_bounds__(256)
void attn_row_kernel(const void* __restrict__ Qv, const void* __restrict__ Kv,
                     const void* __restrict__ Vv, const int* __restrict__ maskp,
                     float* __restrict__ out, float* __restrict__ att)
{
    const int tid = threadIdx.x;
    const int row = blockIdx.x;            // row = bh*S + q
    const int bh  = row >> 11;             // / S_
    const int q   = row & (S_ - 1);
    const int causal = maskp[0];
    const int kmax = causal ? q : (S_ - 1);

    __shared__ float  sS[S_];              // score row -> e row (8 KB)
    __shared__ float4 sPart4[256];         // PV partials: 16 jg x 16 dq (4 KB)
    __shared__ float  sMax[4];
    __shared__ float  sSum[4];

    const size_t base = (size_t)bh * S_ * D_;
    const int lane = tid & 63;
    const int wid  = tid >> 6;

    // ---- dtype sniff, wave-parallel (no barrier, all waves same answer):
    // fp32 misread as bf16 has hot "exponent" fields in the mantissa halves.
    bool isf32;
    {
        u32 w = ((const u32*)Qv)[lane];
        int e0 = (int)((w >> 7)  & 0xFFu);
        int e1 = (int)((w >> 23) & 0xFFu);
        unsigned long long b = __ballot(e0 >= 0x8F || e1 >= 0x8F);
        isf32 = (__popcll(b) >= 4);
    }

    // ---- Q row into registers, pre-scaled by 1/sqrt(64).
    // All lanes read the same 256 B -> L1 broadcast, no LDS in the dot loop.
    float4 qv[16];
    if (isf32) {
        const float4* Q4 = reinterpret_cast<const float4*>(
            (const float*)Qv + base + (size_t)q * D_);
        #pragma unroll
        for (int c = 0; c < 16; ++c) {
            float4 t = Q4[c];
            qv[c] = make_float4(t.x*0.125f, t.y*0.125f, t.z*0.125f, t.w*0.125f);
        }
    } else {
        const ushort4* Q4 = reinterpret_cast<const ushort4*>(
            (const u16*)Qv + base + (size_t)q * D_);
        #pragma unroll
        for (int c = 0; c < 16; ++c) {
            ushort4 t = Q4[c];
            qv[c] = make_float4(bf2f(t.x)*0.125f, bf2f(t.y)*0.125f,
                                bf2f(t.z)*0.125f, bf2f(t.w)*0.125f);
        }
    }

    // ---- scores: sS[j] = Q.K[j]/8 for j <= kmax (masked slots left unwritten;
    // every later read of them is guarded). Per-thread running max fused in.
    float lm = -INFINITY;
    if (isf32) {
        const float4* K4 = reinterpret_cast<const float4*>((const float*)Kv + base);
        for (int off = 0; off <= kmax; off += 512) {
            const int ja = off + tid;       // ja <= 1791 < S_
            const int jb = ja + 256;        // jb <= 2047 < S_
            if (jb <= kmax) {               // common dual case: 32 loads in flight
                const float4* ka = K4 + (size_t)ja * 16;
                const float4* kb = K4 + (size_t)jb * 16;
                float a0=0.f, a1=0.f, b0=0.f, b1=0.f;
                #pragma unroll
                for (int c = 0; c < 16; c += 2) {
                    float4 x0 = ka[c], x1 = ka[c+1];
                    float4 y0 = kb[c], y1 = kb[c+1];
                    a0 += qv[c].x*x0.x + qv[c].y*x0.y + qv[c].z*x0.z + qv[c].w*x0.w;
                    a1 += qv[c+1].x*x1.x + qv[c+1].y*x1.y + qv[c+1].z*x1.z + qv[c+1].w*x1.w;
                    b0 += qv[c].x*y0.x + qv[c].y*y0.y + qv[c].z*y0.z + qv[c].w*y0.w;
                    b1 += qv[c+1].x*y1.x + qv[c+1].y*y1.y + qv[c+1].z*y1.z + qv[c+1].w*y1.w;
                }
                float sa = a0 + a1, sb = b0 + b1;
                sS[ja] = sa; sS[jb] = sb;
                lm = fmaxf(lm, fmaxf(sa, sb));
            } else if (ja <= kmax) {        // boundary wave only
                const float4* ka = K4 + (size_t)ja * 16;
                float a0=0.f, a1=0.f;
                #pragma unroll
                for (int c = 0; c < 16; c += 2) {
                    float4 x0 = ka[c], x1 = ka[c+1];
                    a0 += qv[c].x*x0.x + qv[c].y*x0.y + qv[c].z*x0.z + qv[c].w*x0.w;
                    a1 += qv[c+1].x*x1.x + qv[c+1].y*x1.y + qv[c+1].z*x1.z + qv[c+1].w*x1.w;
                }
                float sa = a0 + a1;
                sS[ja] = sa;
                lm = fmaxf(lm, sa);
            }
        }
    } else {
        const u16* Kh = (const u16*)Kv + base;
        for (int off = 0; off <= kmax; off += 256) {
            const int j = off + tid;
            if (j <= kmax) {
                const ushort4* kr = reinterpret_cast<const ushort4*>(Kh + (size_t)j * D_);
                float a0 = 0.f;
                #pragma unroll
                for (int c = 0; c < 16; ++c) {
                    ushort4 h = kr[c];
                    a0 += qv[c].x*bf2f(h.x) + qv[c].y*bf2f(h.y)
                        + qv[c].z*bf2f(h.z) + qv[c].w*bf2f(h.w);
                }
                sS[j] = a0;
                lm = fmaxf(lm, a0);
            }
        }
    }

    // ---- block max: wave shfl reduce + 4-slot LDS (barrier 1)
    lm = wred_max(lm);
    if (lane == 0) sMax[wid] = lm;
    __syncthreads();
    const float m = fmaxf(fmaxf(sMax[0], sMax[1]), fmaxf(sMax[2], sMax[3]));

    // ---- e = exp(s - m) on own slots (no cross-thread reads), then block sum
    float ls = 0.f;
    for (int j = tid; j <= kmax; j += 256) {
        float e = __expf(sS[j] - m);
        sS[j] = e;
        ls += e;
    }
    ls = wred_sum(ls);
    if (lane == 0) sSum[wid] = ls;
    __syncthreads();                       // barrier 2: also publishes all e
    const float l   = (sSum[0] + sSum[1]) + (sSum[2] + sSum[3]);
    const float inv = 1.f / l;

    // ---- attention row write: p = e * inv (sS keeps raw e for PV; no barrier
    // needed between this and PV). Non-temporal: 512 MiB stream, don't evict K/V.
    {
        const int j0 = tid * 8;            // 256 * 8 == 2048
        const float4* sS4 = reinterpret_cast<const float4*>(sS);
        float4 v0 = sS4[tid*2], v1 = sS4[tid*2 + 1];
        f32x4 p0, p1;
        p0.x = (j0+0 <= kmax) ? v0.x*inv : 0.f;
        p0.y = (j0+1 <= kmax) ? v0.y*inv : 0.f;
        p0.z = (j0+2 <= kmax) ? v0.z*inv : 0.f;
        p0.w = (j0+3 <= kmax) ? v0.w*inv : 0.f;
        p1.x = (j0+4 <= kmax) ? v1.x*inv : 0.f;
        p1.y = (j0+5 <= kmax) ? v1.y*inv : 0.f;
        p1.z = (j0+6 <= kmax) ? v1.z*inv : 0.f;
        p1.w = (j0+7 <= kmax) ? v1.w*inv : 0.f;
        f32x4* attRow4 = reinterpret_cast<f32x4*>(att + (size_t)row * S_ + j0);
        __builtin_nontemporal_store(p0, attRow4 + 0);
        __builtin_nontemporal_store(p1, attRow4 + 1);
    }

    // ---- out[d] = inv * sum_j e_j * V[j][d]
    // 16 j-groups x 16 float4 d-columns; 4-way unroll -> 16 loads in flight.
    const int dq = tid & 15;               // float4 column
    const int jg = tid >> 4;               // j-group
    float4 acc0 = make_float4(0.f,0.f,0.f,0.f);
    float4 acc1 = acc0, acc2 = acc0, acc3 = acc0;
    if (isf32) {
        const float4* V4 = reinterpret_cast<const float4*>((const float*)Vv + base);
        const float4* vp = V4 + (size_t)jg * 16 + dq;
        int j = jg;
        for (; j + 48 <= kmax; j += 64, vp += 1024) {
            float p0 = sS[j], p1 = sS[j+16], p2 = sS[j+32], p3 = sS[j+48];
            float4 v0 = vp[0], v1 = vp[256], v2 = vp[512], v3 = vp[768];
            acc0.x = fmaf(p0, v0.x, acc0.x); acc0.y = fmaf(p0, v0.y, acc0.y);
            acc0.z = fmaf(p0, v0.z, acc0.z); acc0.w = fmaf(p0, v0.w, acc0.w);
            acc1.x = fmaf(p1, v1.x, acc1.x); acc1.y = fmaf(p1, v1.y, acc1.y);
            acc1.z = fmaf(p1, v1.z, acc1.z); acc1.w = fmaf(p1, v1.w, acc1.w);
            acc2.x = fmaf(p2, v2.x, acc2.x); acc2.y = fmaf(p2, v2.y, acc2.y);
            acc2.z = fmaf(p2, v2.z, acc2.z); acc2.w = fmaf(p2, v2.w, acc2.w);
            acc3.x = fmaf(p3, v3.x, acc3.x); acc3.y = fmaf(p3, v3.y, acc3.y);
            acc3.z = fmaf(p3, v3.z, acc3.z); acc3.w = fmaf(p3, v3.w, acc3.w);
        }
        for (; j <= kmax; j += 16, vp += 256) {
            float p0 = sS[j];
            float4 v0 = vp[0];
            acc0.x = fmaf(p0, v0.x, acc0.x); acc0.y = fmaf(p0, v0.y, acc0.y);
            acc0.z = fmaf(p0, v0.z, acc0.z); acc0.w = fmaf(p0, v0.w, acc0.w);
        }
    } else {
        const u16* Vh = (const u16*)Vv + base;
        for (int j = jg; j <= kmax; j += 16) {
            float p0 = sS[j];
            ushort4 h = reinterpret_cast<const ushort4*>(Vh + (size_t)j * D_)[dq];
            acc0.x = fmaf(p0, bf2f(h.x), acc0.x);
            acc0.y = fmaf(p0, bf2f(h.y), acc0.y);
            acc0.z = fmaf(p0, bf2f(h.z), acc0.z);
            acc0.w = fmaf(p0, bf2f(h.w), acc0.w);
        }
    }
    float4 a;
    a.x = (acc0.x + acc1.x) + (acc2.x + acc3.x);
    a.y = (acc0.y + acc1.y) + (acc2.y + acc3.y);
    a.z = (acc0.z + acc1.z) + (acc2.z + acc3.z);
    a.w = (acc0.w + acc1.w) + (acc2.w + acc3.w);
    sPart4[jg * 16 + dq] = a;
    __syncthreads();                       // barrier 3
    if (tid < D_) {
        const float* sp = reinterpret_cast<const float*>(sPart4);
        float o = 0.f;
        #pragma unroll
        for (int g = 0; g < 16; ++g) o += sp[g * 64 + tid];
        out[(size_t)row * D_ + tid] = o * inv;
    }
}

extern "C" void kernel_launch(void* const* d_in, const int* in_sizes, int n_in,
                              void* d_out, int out_size, void* d_ws, size_t ws_size,
                              hipStream_t stream) {
    const void* Q = d_in[0];
    const void* K = d_in[1];
    const void* V = d_in[2];
    const int* mask = (const int*)d_in[3];

    float* out = (float*)d_out;                              // B*H*S*D floats
    float* att = out + (size_t)B_ * H_ * S_ * D_;            // B*H*S*S floats

    const int nrows = B_ * H_ * S_;                          // 65536 blocks
    attn_row_kernel<<<nrows, 256, 0, stream>>>(Q, K, V, mask, out, att);
}

// Round 3
// 1190.588 us; speedup vs baseline: 3.7607x; 2.5160x over previous
//
#include <hip/hip_runtime.h>

// Causal self-attention fwd, B=2, H=16, S=2048, D=64.
// Inputs fp32 (dtype sniff kept as insurance). Outputs fp32:
// d_out = [out (B*H*S*D)] ++ [attention (B*H*S*S)].
//
// Round 3: K/V reuse. QB=4 query rows per block (grid 16384); each K row is
// loaded once per block and dotted against 4 Q rows (Q via block-uniform
// pointer -> scalar loads); each V quad loaded once feeds 4 accumulators.
// VMEM traffic / instruction count drop ~4x vs round 2 (the measured
// bottleneck: VALUBusy 16%, HBM 3.4% -> latency/issue-bound on K/V re-reads).
// LDS: 4 score rows (32 KB), PV partials aliased over sS after a barrier.
// XCD swizzle: contiguous 2048-block chunks per XCD -> 4 MB K/V set per L2.

#define B_ 2
#define H_ 16
#define S_ 2048
#define D_ 64
#define QB 4

typedef unsigned short u16;
typedef unsigned int   u32;
typedef float f32x4 __attribute__((ext_vector_type(4)));

__device__ __forceinline__ float bf2f(u16 h) {
    union { u32 u; float f; } x; x.u = ((u32)h) << 16; return x.f;
}

__device__ __forceinline__ float wred_max(float v) {
    #pragma unroll
    for (int o = 32; o > 0; o >>= 1) v = fmaxf(v, __shfl_xor(v, o, 64));
    return v;
}
__device__ __forceinline__ float wred_sum(float v) {
    #pragma unroll
    for (int o = 32; o > 0; o >>= 1) v += __shfl_xor(v, o, 64);
    return v;
}

__global__ __launch_bounds__(256)
void attn_tile_kernel(const void* __restrict__ Qv, const void* __restrict__ Kv,
                      const void* __restrict__ Vv, const int* __restrict__ maskp,
                      float* __restrict__ out, float* __restrict__ att)
{
    const int tid = threadIdx.x;

    // XCD-aware swizzle (16384 blocks, 8 XCDs, bijective):
    // same-XCD neighbors share 4 heads' K/V = 4 MB = one L2.
    const int bid0 = blockIdx.x;
    const int bid  = (bid0 & 7) * ((B_ * H_ * S_ / QB) >> 3) + (bid0 >> 3);

    const int bh = bid >> 9;               // / (S_/QB) = 512 blocks per bh
    const int q0 = (bid & 511) << 2;       // first of 4 q rows
    const int causal = maskp[0];
    const int km0 = causal ? (q0 + 0) : (S_ - 1);
    const int km1 = causal ? (q0 + 1) : (S_ - 1);
    const int km2 = causal ? (q0 + 2) : (S_ - 1);
    const int km3 = causal ? (q0 + 3) : (S_ - 1);
    const int kmaxB = km3;                 // block-wide bound (uniform)

    __shared__ float sS[QB * S_];          // 4 score rows -> e rows (32 KB)
    __shared__ float sMaxP[4 * QB];        // per-wave partial max
    __shared__ float sSumP[4 * QB];
    __shared__ float sInv[QB];

    const size_t base = (size_t)bh * S_ * D_;
    const int lane = tid & 63;
    const int wid  = tid >> 6;

    // ---- dtype sniff (wave-parallel, uniform result) ----
    bool isf32;
    {
        u32 w = ((const u32*)Qv)[lane];
        int e0 = (int)((w >> 7)  & 0xFFu);
        int e1 = (int)((w >> 23) & 0xFFu);
        unsigned long long b = __ballot(e0 >= 0x8F || e1 >= 0x8F);
        isf32 = (__popcll(b) >= 4);
    }

    // ---- scores: sS[qq][j] = Q[q0+qq] . K[j] (unscaled; /8 folded into exp),
    // masked cells stored as -inf. Q accessed via block-uniform pointer ->
    // scalar loads; K row loaded once per thread, dotted against all 4 Q rows.
    float lm0 = -INFINITY, lm1 = -INFINITY, lm2 = -INFINITY, lm3 = -INFINITY;
    if (isf32) {
        const float4* Q4u = reinterpret_cast<const float4*>(
            (const float*)Qv + base + (size_t)q0 * D_);       // uniform
        const float4* K4 = reinterpret_cast<const float4*>((const float*)Kv + base);
        int off = 0;
        for (; off + 255 <= kmaxB; off += 256) {              // full tiles, uniform
            const int j = off + tid;
            const float4* kr = K4 + (size_t)j * 16;
            float4 kq[16];
            #pragma unroll
            for (int c = 0; c < 16; ++c) kq[c] = kr[c];
            float d0 = 0.f, d1 = 0.f, d2 = 0.f, d3 = 0.f;
            #pragma unroll
            for (int c = 0; c < 16; ++c) {
                float4 a0 = Q4u[c], a1 = Q4u[16 + c], a2 = Q4u[32 + c], a3 = Q4u[48 + c];
                d0 += a0.x*kq[c].x + a0.y*kq[c].y + a0.z*kq[c].z + a0.w*kq[c].w;
                d1 += a1.x*kq[c].x + a1.y*kq[c].y + a1.z*kq[c].z + a1.w*kq[c].w;
                d2 += a2.x*kq[c].x + a2.y*kq[c].y + a2.z*kq[c].z + a2.w*kq[c].w;
                d3 += a3.x*kq[c].x + a3.y*kq[c].y + a3.z*kq[c].z + a3.w*kq[c].w;
            }
            float s0 = (j <= km0) ? d0 : -INFINITY;
            float s1 = (j <= km1) ? d1 : -INFINITY;
            float s2 = (j <= km2) ? d2 : -INFINITY;
            float s3 = (j <= km3) ? d3 : -INFINITY;
            sS[0*S_ + j] = s0; lm0 = fmaxf(lm0, s0);
            sS[1*S_ + j] = s1; lm1 = fmaxf(lm1, s1);
            sS[2*S_ + j] = s2; lm2 = fmaxf(lm2, s2);
            sS[3*S_ + j] = s3; lm3 = fmaxf(lm3, s3);
        }
        {   // tail tile (divergent guard)
            const int j = off + tid;
            if (j <= kmaxB) {
                const float4* kr = K4 + (size_t)j * 16;
                float d0 = 0.f, d1 = 0.f, d2 = 0.f, d3 = 0.f;
                #pragma unroll
                for (int c = 0; c < 16; ++c) {
                    float4 kc = kr[c];
                    float4 a0 = Q4u[c], a1 = Q4u[16 + c], a2 = Q4u[32 + c], a3 = Q4u[48 + c];
                    d0 += a0.x*kc.x + a0.y*kc.y + a0.z*kc.z + a0.w*kc.w;
                    d1 += a1.x*kc.x + a1.y*kc.y + a1.z*kc.z + a1.w*kc.w;
                    d2 += a2.x*kc.x + a2.y*kc.y + a2.z*kc.z + a2.w*kc.w;
                    d3 += a3.x*kc.x + a3.y*kc.y + a3.z*kc.z + a3.w*kc.w;
                }
                float s0 = (j <= km0) ? d0 : -INFINITY;
                float s1 = (j <= km1) ? d1 : -INFINITY;
                float s2 = (j <= km2) ? d2 : -INFINITY;
                float s3 = (j <= km3) ? d3 : -INFINITY;
                sS[0*S_ + j] = s0; lm0 = fmaxf(lm0, s0);
                sS[1*S_ + j] = s1; lm1 = fmaxf(lm1, s1);
                sS[2*S_ + j] = s2; lm2 = fmaxf(lm2, s2);
                sS[3*S_ + j] = s3; lm3 = fmaxf(lm3, s3);
            }
        }
    } else {
        const u16* Qh = (const u16*)Qv + base + (size_t)q0 * D_;   // uniform
        const u16* Kh = (const u16*)Kv + base;
        for (int off = 0; off <= kmaxB; off += 256) {
            const int j = off + tid;
            if (j <= kmaxB) {
                const u16* kr = Kh + (size_t)j * D_;
                float d0 = 0.f, d1 = 0.f, d2 = 0.f, d3 = 0.f;
                #pragma unroll
                for (int c = 0; c < D_; ++c) {
                    float kc = bf2f(kr[c]);
                    d0 += bf2f(Qh[c])        * kc;
                    d1 += bf2f(Qh[64 + c])   * kc;
                    d2 += bf2f(Qh[128 + c])  * kc;
                    d3 += bf2f(Qh[192 + c])  * kc;
                }
                float s0 = (j <= km0) ? d0 : -INFINITY;
                float s1 = (j <= km1) ? d1 : -INFINITY;
                float s2 = (j <= km2) ? d2 : -INFINITY;
                float s3 = (j <= km3) ? d3 : -INFINITY;
                sS[0*S_ + j] = s0; lm0 = fmaxf(lm0, s0);
                sS[1*S_ + j] = s1; lm1 = fmaxf(lm1, s1);
                sS[2*S_ + j] = s2; lm2 = fmaxf(lm2, s2);
                sS[3*S_ + j] = s3; lm3 = fmaxf(lm3, s3);
            }
        }
    }

    // ---- block max per row (barrier 1) ----
    lm0 = wred_max(lm0); lm1 = wred_max(lm1);
    lm2 = wred_max(lm2); lm3 = wred_max(lm3);
    if (lane == 0) {
        sMaxP[wid*QB + 0] = lm0; sMaxP[wid*QB + 1] = lm1;
        sMaxP[wid*QB + 2] = lm2; sMaxP[wid*QB + 3] = lm3;
    }
    __syncthreads();
    const float m0 = fmaxf(fmaxf(sMaxP[0], sMaxP[QB]), fmaxf(sMaxP[2*QB], sMaxP[3*QB]));
    const float m1 = fmaxf(fmaxf(sMaxP[1], sMaxP[QB+1]), fmaxf(sMaxP[2*QB+1], sMaxP[3*QB+1]));
    const float m2 = fmaxf(fmaxf(sMaxP[2], sMaxP[QB+2]), fmaxf(sMaxP[2*QB+2], sMaxP[3*QB+2]));
    const float m3 = fmaxf(fmaxf(sMaxP[3], sMaxP[QB+3]), fmaxf(sMaxP[2*QB+3], sMaxP[3*QB+3]));

    // ---- e = exp((s - m)/8), in place; masked cells (-inf) -> 0 ----
    float ls0 = 0.f, ls1 = 0.f, ls2 = 0.f, ls3 = 0.f;
    for (int j = tid; j <= kmaxB; j += 256) {
        float e0 = __expf((sS[0*S_ + j] - m0) * 0.125f);
        float e1 = __expf((sS[1*S_ + j] - m1) * 0.125f);
        float e2 = __expf((sS[2*S_ + j] - m2) * 0.125f);
        float e3 = __expf((sS[3*S_ + j] - m3) * 0.125f);
        sS[0*S_ + j] = e0; ls0 += e0;
        sS[1*S_ + j] = e1; ls1 += e1;
        sS[2*S_ + j] = e2; ls2 += e2;
        sS[3*S_ + j] = e3; ls3 += e3;
    }
    ls0 = wred_sum(ls0); ls1 = wred_sum(ls1);
    ls2 = wred_sum(ls2); ls3 = wred_sum(ls3);
    if (lane == 0) {
        sSumP[wid*QB + 0] = ls0; sSumP[wid*QB + 1] = ls1;
        sSumP[wid*QB + 2] = ls2; sSumP[wid*QB + 3] = ls3;
    }
    __syncthreads();                       // barrier 2: publishes e rows too
    const float inv0 = 1.f / (((sSumP[0] + sSumP[QB]) + (sSumP[2*QB] + sSumP[3*QB])));
    const float inv1 = 1.f / (((sSumP[1] + sSumP[QB+1]) + (sSumP[2*QB+1] + sSumP[3*QB+1])));
    const float inv2 = 1.f / (((sSumP[2] + sSumP[QB+2]) + (sSumP[2*QB+2] + sSumP[3*QB+2])));
    const float inv3 = 1.f / (((sSumP[3] + sSumP[QB+3]) + (sSumP[2*QB+3] + sSumP[3*QB+3])));
    if (tid == 0) { sInv[0] = inv0; sInv[1] = inv1; sInv[2] = inv2; sInv[3] = inv3; }

    // ---- attention rows: p = e*inv for j<=kmaxB else 0; nt stores ----
    {
        const int j0 = tid * 8;
        const size_t arow = ((size_t)bh * S_ + q0) * S_;
        #define ATT_WRITE(QQ, INVQ)                                            \
        {                                                                      \
            const float4* s4 = reinterpret_cast<const float4*>(sS + QQ*S_);    \
            float4 v0 = s4[tid*2], v1 = s4[tid*2 + 1];                         \
            f32x4 p0, p1;                                                      \
            p0.x = (j0+0 <= kmaxB) ? v0.x*INVQ : 0.f;                          \
            p0.y = (j0+1 <= kmaxB) ? v0.y*INVQ : 0.f;                          \
            p0.z = (j0+2 <= kmaxB) ? v0.z*INVQ : 0.f;                          \
            p0.w = (j0+3 <= kmaxB) ? v0.w*INVQ : 0.f;                          \
            p1.x = (j0+4 <= kmaxB) ? v1.x*INVQ : 0.f;                          \
            p1.y = (j0+5 <= kmaxB) ? v1.y*INVQ : 0.f;                          \
            p1.z = (j0+6 <= kmaxB) ? v1.z*INVQ : 0.f;                          \
            p1.w = (j0+7 <= kmaxB) ? v1.w*INVQ : 0.f;                          \
            f32x4* a4 = reinterpret_cast<f32x4*>(att + arow + (size_t)QQ*S_ + j0); \
            __builtin_nontemporal_store(p0, a4 + 0);                           \
            __builtin_nontemporal_store(p1, a4 + 1);                           \
        }
        ATT_WRITE(0, inv0) ATT_WRITE(1, inv1) ATT_WRITE(2, inv2) ATT_WRITE(3, inv3)
        #undef ATT_WRITE
    }

    // ---- PV: acc[qq] += e[qq][j] * V[j][dq-quad]; V quad loaded once ----
    const int dq = tid & 15;
    const int jg = tid >> 4;
    float4 acc0 = make_float4(0.f,0.f,0.f,0.f);
    float4 acc1 = acc0, acc2 = acc0, acc3 = acc0;
    if (isf32) {
        const float4* V4 = reinterpret_cast<const float4*>((const float*)Vv + base);
        const float4* vp = V4 + (size_t)jg * 16 + dq;
        #pragma unroll 4
        for (int j = jg; j <= kmaxB; j += 16, vp += 256) {
            float4 v0 = vp[0];
            float p0 = sS[0*S_ + j], p1 = sS[1*S_ + j];
            float p2 = sS[2*S_ + j], p3 = sS[3*S_ + j];
            acc0.x = fmaf(p0, v0.x, acc0.x); acc0.y = fmaf(p0, v0.y, acc0.y);
            acc0.z = fmaf(p0, v0.z, acc0.z); acc0.w = fmaf(p0, v0.w, acc0.w);
            acc1.x = fmaf(p1, v0.x, acc1.x); acc1.y = fmaf(p1, v0.y, acc1.y);
            acc1.z = fmaf(p1, v0.z, acc1.z); acc1.w = fmaf(p1, v0.w, acc1.w);
            acc2.x = fmaf(p2, v0.x, acc2.x); acc2.y = fmaf(p2, v0.y, acc2.y);
            acc2.z = fmaf(p2, v0.z, acc2.z); acc2.w = fmaf(p2, v0.w, acc2.w);
            acc3.x = fmaf(p3, v0.x, acc3.x); acc3.y = fmaf(p3, v0.y, acc3.y);
            acc3.z = fmaf(p3, v0.z, acc3.z); acc3.w = fmaf(p3, v0.w, acc3.w);
        }
    } else {
        const u16* Vh = (const u16*)Vv + base;
        for (int j = jg; j <= kmaxB; j += 16) {
            ushort4 h = reinterpret_cast<const ushort4*>(Vh + (size_t)j * D_)[dq];
            float vx = bf2f(h.x), vy = bf2f(h.y), vz = bf2f(h.z), vw = bf2f(h.w);
            float p0 = sS[0*S_ + j], p1 = sS[1*S_ + j];
            float p2 = sS[2*S_ + j], p3 = sS[3*S_ + j];
            acc0.x = fmaf(p0, vx, acc0.x); acc0.y = fmaf(p0, vy, acc0.y);
            acc0.z = fmaf(p0, vz, acc0.z); acc0.w = fmaf(p0, vw, acc0.w);
            acc1.x = fmaf(p1, vx, acc1.x); acc1.y = fmaf(p1, vy, acc1.y);
            acc1.z = fmaf(p1, vz, acc1.z); acc1.w = fmaf(p1, vw, acc1.w);
            acc2.x = fmaf(p2, vx, acc2.x); acc2.y = fmaf(p2, vy, acc2.y);
            acc2.z = fmaf(p2, vz, acc2.z); acc2.w = fmaf(p2, vw, acc2.w);
            acc3.x = fmaf(p3, vx, acc3.x); acc3.y = fmaf(p3, vy, acc3.y);
            acc3.z = fmaf(p3, vz, acc3.z); acc3.w = fmaf(p3, vw, acc3.w);
        }
    }

    // ---- partials aliased over sS (16 KB of the 32 KB), then reduce ----
    __syncthreads();                       // barrier 3: all sS reads done
    float4* sPart4 = reinterpret_cast<float4*>(sS);   // [qq][jg][dq] float4
    sPart4[0*256 + jg*16 + dq] = acc0;
    sPart4[1*256 + jg*16 + dq] = acc1;
    sPart4[2*256 + jg*16 + dq] = acc2;
    sPart4[3*256 + jg*16 + dq] = acc3;
    __syncthreads();                       // barrier 4
    {
        const int qq = tid >> 6;           // 4 q x 64 d = 256 threads
        const int d  = tid & 63;
        float o = 0.f;
        #pragma unroll
        for (int g = 0; g < 16; ++g) o += sS[qq*1024 + g*64 + d];
        out[((size_t)bh * S_ + q0 + qq) * D_ + d] = o * sInv[qq];
    }
}

extern "C" void kernel_launch(void* const* d_in, const int* in_sizes, int n_in,
                              void* d_out, int out_size, void* d_ws, size_t ws_size,
                              hipStream_t stream) {
    const void* Q = d_in[0];
    const void* K = d_in[1];
    const void* V = d_in[2];
    const int* mask = (const int*)d_in[3];

    float* out = (float*)d_out;                              // B*H*S*D floats
    float* att = out + (size_t)B_ * H_ * S_ * D_;            // B*H*S*S floats

    const int nblk = (B_ * H_ * S_) / QB;                    // 16384 blocks
    attn_tile_kernel<<<nblk, 256, 0, stream>>>(Q, K, V, mask, out, att);
}